// Round 2
// baseline (767.190 us; speedup 1.0000x reference)
//
#include <hip/hip_runtime.h>
#include <math.h>

#define DIM 256
#define NSLOTS 8
#define TOKENS 4096
#define BATCH 64
#define NCHUNK 32

// ---------- helpers ----------
__device__ __forceinline__ float wsum(float v) {
#pragma unroll
  for (int m = 32; m >= 1; m >>= 1) v += __shfl_xor(v, m);
  return v;
}
__device__ __forceinline__ float wmax(float v) {
#pragma unroll
  for (int m = 32; m >= 1; m >>= 1) v = fmaxf(v, __shfl_xor(v, m));
  return v;
}
__device__ __forceinline__ unsigned short f2bf(float f) {
  unsigned u = __float_as_uint(f);
  u += 0x7fffu + ((u >> 16) & 1u);
  return (unsigned short)(u >> 16);
}
__device__ __forceinline__ float bflo(unsigned p) { return __uint_as_float(p << 16); }
__device__ __forceinline__ float bfhi(unsigned p) { return __uint_as_float(p & 0xffff0000u); }
__device__ __forceinline__ float sigmf(float x) { return 1.f / (1.f + expf(-x)); }

// ---------- K1: LN(inputs) -> x (bf16, packed pairs in uint) ----------
// one wave per row; 4 rows per 256-thread block
__global__ __launch_bounds__(256) void k_ln_in(const float* __restrict__ in,
                                               const float* __restrict__ g,
                                               const float* __restrict__ b,
                                               unsigned* __restrict__ x) {
  int row = blockIdx.x * 4 + (threadIdx.x >> 6);
  int lane = threadIdx.x & 63;
  const float* p = in + (size_t)row * DIM + lane * 4;
  float4 v = *(const float4*)p;
  float s  = wsum(v.x + v.y + v.z + v.w);
  float sq = wsum(v.x * v.x + v.y * v.y + v.z * v.z + v.w * v.w);
  float mu = s * (1.f / 256.f);
  float var = sq * (1.f / 256.f) - mu * mu;
  float rs = rsqrtf(var + 1e-5f);
  float4 gg = *(const float4*)(g + lane * 4);
  float4 bb = *(const float4*)(b + lane * 4);
  float y0 = (v.x - mu) * rs * gg.x + bb.x;
  float y1 = (v.y - mu) * rs * gg.y + bb.y;
  float y2 = (v.z - mu) * rs * gg.z + bb.z;
  float y3 = (v.w - mu) * rs * gg.w + bb.w;
  uint2 o;
  o.x = (unsigned)f2bf(y0) | ((unsigned)f2bf(y1) << 16);
  o.y = (unsigned)f2bf(y2) | ((unsigned)f2bf(y3) << 16);
  *(uint2*)(x + (size_t)row * 128 + lane * 2) = o;
}

// ---------- K2: slots = mu + exp(logsigma)*noise ----------
__global__ __launch_bounds__(256) void k_init(const float* __restrict__ mu,
                                              const float* __restrict__ ls,
                                              const float* __restrict__ noise,
                                              float* __restrict__ slots) {
  int i = blockIdx.x * 256 + threadIdx.x;  // 131072 total
  int sd = i & 2047;
  slots[i] = mu[sd] + expf(ls[sd]) * noise[i];
}

// ---------- K3: qw[n,s,d] = scale * sum_e (LN(slots)[s]@Wq^T)[e] * Wk[e,d] ----------
// one block per batch n
__global__ __launch_bounds__(256) void k_qw(const float* __restrict__ slots,
                                            const float* __restrict__ g,
                                            const float* __restrict__ b,
                                            const float* __restrict__ Wq,
                                            const float* __restrict__ Wk,
                                            float* __restrict__ qw) {
  __shared__ float ln[NSLOTS][DIM];
  __shared__ float q[NSLOTS][DIM];
  int n = blockIdx.x;
  int tid = threadIdx.x, lane = tid & 63, wid = tid >> 6;
  const float* sp = slots + (size_t)n * 2048;
  for (int s = wid; s < 8; s += 4) {
    float4 v = *(const float4*)(sp + s * 256 + lane * 4);
    float sum = wsum(v.x + v.y + v.z + v.w);
    float sq  = wsum(v.x * v.x + v.y * v.y + v.z * v.z + v.w * v.w);
    float mu = sum * (1.f / 256.f);
    float var = sq * (1.f / 256.f) - mu * mu;
    float rs = rsqrtf(var + 1e-5f);
    int j = lane * 4;
    ln[s][j + 0] = (v.x - mu) * rs * g[j + 0] + b[j + 0];
    ln[s][j + 1] = (v.y - mu) * rs * g[j + 1] + b[j + 1];
    ln[s][j + 2] = (v.z - mu) * rs * g[j + 2] + b[j + 2];
    ln[s][j + 3] = (v.w - mu) * rs * g[j + 3] + b[j + 3];
  }
  __syncthreads();
  {
    int e = tid;
    float acc[8] = {0, 0, 0, 0, 0, 0, 0, 0};
    const float* wr = Wq + (size_t)e * 256;
    for (int d = 0; d < 256; ++d) {
      float w = wr[d];
#pragma unroll
      for (int s = 0; s < 8; ++s) acc[s] += ln[s][d] * w;
    }
#pragma unroll
    for (int s = 0; s < 8; ++s) q[s][e] = acc[s];
  }
  __syncthreads();
  {
    int d = tid;
    float acc[8] = {0, 0, 0, 0, 0, 0, 0, 0};
    for (int e = 0; e < 256; ++e) {
      float w = Wk[(size_t)e * 256 + d];
#pragma unroll
      for (int s = 0; s < 8; ++s) acc[s] += q[s][e] * w;
    }
#pragma unroll
    for (int s = 0; s < 8; ++s) qw[(size_t)n * 2048 + s * 256 + d] = acc[s] * 0.0625f;
  }
}

// ---------- K4: logits[n,s,t] = sum_d qw[n,s,d] * x[n,t,d] ----------
// grid (64 token-tiles of 64, BATCH); 256 threads
__global__ __launch_bounds__(256) void k_logits(const unsigned* __restrict__ x,
                                                const float* __restrict__ qwp,
                                                float* __restrict__ logits) {
  __shared__ float qws[8][256];
  __shared__ unsigned xs[64][129];  // stride 129 words -> conflict-free rows
  int n = blockIdx.y, t0 = blockIdx.x * 64;
  int tid = threadIdx.x;
  for (int i = tid; i < 2048; i += 256) qws[i >> 8][i & 255] = qwp[(size_t)n * 2048 + i];
  const unsigned* xp = x + ((size_t)n * TOKENS + t0) * 128;
#pragma unroll
  for (int it = 0; it < 16; ++it) {
    int tok = it * 4 + (tid >> 6);
    int w0 = (tid & 63) * 2;
    uint2 v = *(const uint2*)(xp + (size_t)tok * 128 + w0);
    xs[tok][w0] = v.x;
    xs[tok][w0 + 1] = v.y;
  }
  __syncthreads();
  int tl = tid & 63, wv = tid >> 6;  // wave handles slots wv and wv+4
  float a0 = 0.f, a1 = 0.f;
#pragma unroll 4
  for (int c = 0; c < 64; ++c) {
    unsigned p0 = xs[tl][2 * c], p1 = xs[tl][2 * c + 1];
    float4 w0 = *(const float4*)&qws[wv][4 * c];
    float4 w1 = *(const float4*)&qws[wv + 4][4 * c];
    float x0 = bflo(p0), x1 = bfhi(p0), x2 = bflo(p1), x3 = bfhi(p1);
    a0 += x0 * w0.x + x1 * w0.y + x2 * w0.z + x3 * w0.w;
    a1 += x0 * w1.x + x1 * w1.y + x2 * w1.z + x3 * w1.w;
  }
  size_t ob = ((size_t)n * 8 + wv) * TOKENS + t0 + tl;
  logits[ob] = a0;
  logits[ob + (size_t)4 * TOKENS] = a1;
}

// ---------- K5: softmax over t (in place) + 1e-8 renorm ----------
__global__ __launch_bounds__(256) void k_softmax(float* __restrict__ L) {
  __shared__ float red[8];
  size_t base = (size_t)blockIdx.x * TOKENS;
  int tid = threadIdx.x, wid = tid >> 6, lane = tid & 63;
  float4 v[4];
  float m = -3.4e38f;
#pragma unroll
  for (int k = 0; k < 4; ++k) {
    v[k] = *(const float4*)(L + base + (size_t)(k * 256 + tid) * 4);
    m = fmaxf(m, fmaxf(fmaxf(v[k].x, v[k].y), fmaxf(v[k].z, v[k].w)));
  }
  m = wmax(m);
  if (lane == 0) red[wid] = m;
  __syncthreads();
  m = fmaxf(fmaxf(red[0], red[1]), fmaxf(red[2], red[3]));
  float ssum = 0.f;
#pragma unroll
  for (int k = 0; k < 4; ++k) {
    v[k].x = expf(v[k].x - m); v[k].y = expf(v[k].y - m);
    v[k].z = expf(v[k].z - m); v[k].w = expf(v[k].w - m);
    ssum += v[k].x + v[k].y + v[k].z + v[k].w;
  }
  ssum = wsum(ssum);
  if (lane == 0) red[4 + wid] = ssum;
  __syncthreads();
  ssum = red[4] + red[5] + red[6] + red[7];
  float inv = 1.f / (ssum * (1.f + 1e-8f));
#pragma unroll
  for (int k = 0; k < 4; ++k) {
    v[k].x *= inv; v[k].y *= inv; v[k].z *= inv; v[k].w *= inv;
    *(float4*)(L + base + (size_t)(k * 256 + tid) * 4) = v[k];
  }
}

// ---------- K6: partial AX[n,c,s,d] = sum_{t in chunk} attn[n,s,t]*x[n,t,d] ----------
// grid (NCHUNK, BATCH), 128 threads; each thread owns one packed-pair column
__global__ __launch_bounds__(128) void k_ax(const unsigned* __restrict__ x,
                                            const float* __restrict__ attn,
                                            float* __restrict__ part) {
  __shared__ float at[8][128];
  int n = blockIdx.y, c = blockIdx.x, t0 = c * 128;
  int tid = threadIdx.x;
  for (int i = tid; i < 1024; i += 128)
    at[i >> 7][i & 127] = attn[((size_t)n * 8 + (i >> 7)) * TOKENS + t0 + (i & 127)];
  __syncthreads();
  const unsigned* xp = x + ((size_t)n * TOKENS + t0) * 128 + tid;
  float a0[8] = {0, 0, 0, 0, 0, 0, 0, 0};
  float a1[8] = {0, 0, 0, 0, 0, 0, 0, 0};
  for (int t = 0; t < 128; ++t) {
    unsigned p = xp[(size_t)t * 128];
    float xl = bflo(p), xh = bfhi(p);
#pragma unroll
    for (int s = 0; s < 8; ++s) {
      float w = at[s][t];
      a0[s] += w * xl;
      a1[s] += w * xh;
    }
  }
  float* pp = part + (((size_t)n * NCHUNK + c) * 8) * 256;
#pragma unroll
  for (int s = 0; s < 8; ++s) {
    pp[s * 256 + tid * 2]     = a0[s];
    pp[s * 256 + tid * 2 + 1] = a1[s];
  }
}

// ---------- K7: reduce partials, updates=AX@Wv^T, GRU, LN, MLP -> new slots ----------
// one block (1024 threads) per batch n; in-place slots update is safe (block-local n)
__global__ __launch_bounds__(1024) void k_update(
    const float* __restrict__ part, const float* __restrict__ slots_in,
    const float* __restrict__ Wv, const float* __restrict__ W_ih,
    const float* __restrict__ W_hh, const float* __restrict__ b_ih,
    const float* __restrict__ b_hh, const float* __restrict__ W1,
    const float* __restrict__ b1, const float* __restrict__ W2,
    const float* __restrict__ b2, const float* __restrict__ g2,
    const float* __restrict__ bt2, float* __restrict__ slots_out) {
  __shared__ float ax[8][256];
  __shared__ float sp[8][256];
  __shared__ float upd[8][256];
  __shared__ float gi[8][768];
  __shared__ float gh[8][768];
  __shared__ float sn[8][256];
  __shared__ float lnv[8][256];
  __shared__ float hid[8][256];
  __shared__ float red[32];
  int n = blockIdx.x, tid = threadIdx.x;
  // 1. reduce 32 partial chunks; load slots_prev
  for (int i = tid; i < 2048; i += 1024) {
    int s = i >> 8, d = i & 255;
    float a = 0.f;
    const float* pp = part + (size_t)n * NCHUNK * 2048 + s * 256 + d;
#pragma unroll
    for (int c = 0; c < NCHUNK; ++c) a += pp[(size_t)c * 2048];
    ax[s][d] = a;
    sp[s][d] = slots_in[(size_t)n * 2048 + i];
  }
  __syncthreads();
  // 2. updates[s][e] = sum_d ax[s][d] * Wv[e][d]
  {
    int e = tid & 255, gq = tid >> 8;
    float A0 = 0.f, A1 = 0.f;
    const float* wr = Wv + (size_t)e * 256;
    for (int d = 0; d < 256; ++d) {
      float w = wr[d];
      A0 += ax[gq][d] * w;
      A1 += ax[gq + 4][d] * w;
    }
    upd[gq][e] = A0;
    upd[gq + 4][e] = A1;
  }
  __syncthreads();
  // 3. gi/gh = {upd,sp} @ W^T + b  (each task: one 768-row for all 8 slots)
  for (int idx = tid; idx < 1536; idx += 1024) {
    bool ih = idx < 768;
    int j = ih ? idx : idx - 768;   // FIX: 768 is not a power of two; idx&767 was wrong
    const float* W = ih ? W_ih : W_hh;
    const float* src = ih ? &upd[0][0] : &sp[0][0];
    const float* wr = W + (size_t)j * 256;
    float a[8] = {0, 0, 0, 0, 0, 0, 0, 0};
    for (int d = 0; d < 256; ++d) {
      float w = wr[d];
#pragma unroll
      for (int s = 0; s < 8; ++s) a[s] += src[s * 256 + d] * w;
    }
    float bb = ih ? b_ih[j] : b_hh[j];
    float* dst = ih ? &gi[0][0] : &gh[0][0];
#pragma unroll
    for (int s = 0; s < 8; ++s) dst[s * 768 + j] = a[s] + bb;
  }
  __syncthreads();
  // 4. gates -> new slots (pre-MLP)
  for (int i = tid; i < 2048; i += 1024) {
    int s = i >> 8, j = i & 255;
    float r = sigmf(gi[s][j] + gh[s][j]);
    float z = sigmf(gi[s][j + 256] + gh[s][j + 256]);
    float h = tanhf(gi[s][j + 512] + r * gh[s][j + 512]);
    sn[s][j] = (1.f - z) * h + z * sp[s][j];
  }
  __syncthreads();
  // 5. LN(sn) with ln_mlp params
  {
    int s = tid >> 7, q = tid & 127;
    float v0 = sn[s][q], v1 = sn[s][q + 128];
    float ps = wsum(v0 + v1);
    float pq = wsum(v0 * v0 + v1 * v1);
    int wid = tid >> 6;
    if ((tid & 63) == 0) { red[wid] = ps; red[16 + wid] = pq; }
    __syncthreads();
    float ssum = red[s << 1] + red[(s << 1) + 1];
    float sqq  = red[16 + (s << 1)] + red[16 + (s << 1) + 1];
    float mu = ssum * (1.f / 256.f);
    float var = sqq * (1.f / 256.f) - mu * mu;
    float rs = rsqrtf(var + 1e-5f);
    lnv[s][q]       = (v0 - mu) * rs * g2[q] + bt2[q];
    lnv[s][q + 128] = (v1 - mu) * rs * g2[q + 128] + bt2[q + 128];
  }
  __syncthreads();
  // 6. hid = relu(lnv @ W1^T + b1)
  {
    int e = tid & 255, gq = tid >> 8;
    float A0 = 0.f, A1 = 0.f;
    const float* wr = W1 + (size_t)e * 256;
    for (int d = 0; d < 256; ++d) {
      float w = wr[d];
      A0 += lnv[gq][d] * w;
      A1 += lnv[gq + 4][d] * w;
    }
    hid[gq][e]     = fmaxf(A0 + b1[e], 0.f);
    hid[gq + 4][e] = fmaxf(A1 + b1[e], 0.f);
  }
  __syncthreads();
  // 7. out = sn + hid @ W2^T + b2
  {
    int e = tid & 255, gq = tid >> 8;
    float A0 = 0.f, A1 = 0.f;
    const float* wr = W2 + (size_t)e * 256;
    for (int d = 0; d < 256; ++d) {
      float w = wr[d];
      A0 += hid[gq][d] * w;
      A1 += hid[gq + 4][d] * w;
    }
    slots_out[(size_t)n * 2048 + gq * 256 + e]       = sn[gq][e] + A0 + b2[e];
    slots_out[(size_t)n * 2048 + (gq + 4) * 256 + e] = sn[gq + 4][e] + A1 + b2[e];
  }
}

extern "C" void kernel_launch(void* const* d_in, const int* in_sizes, int n_in,
                              void* d_out, int out_size, void* d_ws, size_t ws_size,
                              hipStream_t stream) {
  (void)in_sizes; (void)n_in; (void)out_size; (void)ws_size;
  const float* inputs = (const float*)d_in[0];
  const float* noise  = (const float*)d_in[1];
  const float* smu    = (const float*)d_in[2];
  const float* slsig  = (const float*)d_in[3];
  const float* Wq     = (const float*)d_in[4];
  const float* Wk     = (const float*)d_in[5];
  const float* Wv     = (const float*)d_in[6];
  const float* W_ih   = (const float*)d_in[7];
  const float* W_hh   = (const float*)d_in[8];
  const float* b_ih   = (const float*)d_in[9];
  const float* b_hh   = (const float*)d_in[10];
  const float* W1     = (const float*)d_in[11];
  const float* b1     = (const float*)d_in[12];
  const float* W2     = (const float*)d_in[13];
  const float* b2     = (const float*)d_in[14];
  const float* lin_g  = (const float*)d_in[15];
  const float* lin_b  = (const float*)d_in[16];
  const float* lsl_g  = (const float*)d_in[17];
  const float* lsl_b  = (const float*)d_in[18];
  const float* lml_g  = (const float*)d_in[19];
  const float* lml_b  = (const float*)d_in[20];
  float* out = (float*)d_out;
  char* ws = (char*)d_ws;
  unsigned* x   = (unsigned*)ws;                                   // 134217728 B (bf16 x)
  float* logits = (float*)(ws + 134217728);                        // 8388608 B
  float* qw     = (float*)(ws + 134217728 + 8388608);              // 524288 B
  float* part   = (float*)(ws + 134217728 + 8388608 + 524288);     // 16777216 B

  k_ln_in<<<dim3(BATCH * TOKENS / 4), 256, 0, stream>>>(inputs, lin_g, lin_b, x);
  k_init<<<dim3(512), 256, 0, stream>>>(smu, slsig, noise, out);
  for (int it = 0; it < 3; ++it) {
    k_qw<<<dim3(BATCH), 256, 0, stream>>>(out, lsl_g, lsl_b, Wq, Wk, qw);
    k_logits<<<dim3(64, BATCH), 256, 0, stream>>>(x, qw, logits);
    k_softmax<<<dim3(512), 256, 0, stream>>>(logits);
    k_ax<<<dim3(NCHUNK, BATCH), 128, 0, stream>>>(x, logits, part);
    k_update<<<dim3(BATCH), 1024, 0, stream>>>(part, out, Wv, W_ih, W_hh, b_ih,
                                               b_hh, W1, b1, W2, b2, lml_g, lml_b, out);
  }
}

// Round 3
// 616.376 us; speedup vs baseline: 1.2447x; 1.2447x over previous
//
#include <hip/hip_runtime.h>
#include <math.h>

#define DIM 256
#define NSLOTS 8
#define TOKENS 4096
#define BATCH 64
#define NCHUNK 32

// ---------- helpers ----------
__device__ __forceinline__ float wsum(float v) {
#pragma unroll
  for (int m = 32; m >= 1; m >>= 1) v += __shfl_xor(v, m);
  return v;
}
__device__ __forceinline__ float wmax(float v) {
#pragma unroll
  for (int m = 32; m >= 1; m >>= 1) v = fmaxf(v, __shfl_xor(v, m));
  return v;
}
__device__ __forceinline__ unsigned short f2bf(float f) {
  unsigned u = __float_as_uint(f);
  u += 0x7fffu + ((u >> 16) & 1u);
  return (unsigned short)(u >> 16);
}
__device__ __forceinline__ float bflo(unsigned p) { return __uint_as_float(p << 16); }
__device__ __forceinline__ float bfhi(unsigned p) { return __uint_as_float(p & 0xffff0000u); }
__device__ __forceinline__ float sigmf(float x) { return 1.f / (1.f + expf(-x)); }

// ---------- K0: 32x32 tiled transpose src[R][C] -> dst[C][R] ----------
__global__ __launch_bounds__(256) void k_tr(const float* __restrict__ src,
                                            float* __restrict__ dst, int R, int C) {
  __shared__ float t[32][33];
  int c0 = blockIdx.x * 32, r0 = blockIdx.y * 32;
  int ci = threadIdx.x & 31, r8 = threadIdx.x >> 5;
#pragma unroll
  for (int k = 0; k < 4; ++k) {
    int r = r8 + k * 8;
    t[r][ci] = src[(size_t)(r0 + r) * C + c0 + ci];
  }
  __syncthreads();
#pragma unroll
  for (int k = 0; k < 4; ++k) {
    int r = r8 + k * 8;
    dst[(size_t)(c0 + r) * R + r0 + ci] = t[ci][r];
  }
}

// ---------- K1: LN(inputs) -> x (bf16, packed pairs in uint) ----------
__global__ __launch_bounds__(256) void k_ln_in(const float* __restrict__ in,
                                               const float* __restrict__ g,
                                               const float* __restrict__ b,
                                               unsigned* __restrict__ x) {
  int row = blockIdx.x * 4 + (threadIdx.x >> 6);
  int lane = threadIdx.x & 63;
  const float* p = in + (size_t)row * DIM + lane * 4;
  float4 v = *(const float4*)p;
  float s  = wsum(v.x + v.y + v.z + v.w);
  float sq = wsum(v.x * v.x + v.y * v.y + v.z * v.z + v.w * v.w);
  float mu = s * (1.f / 256.f);
  float var = sq * (1.f / 256.f) - mu * mu;
  float rs = rsqrtf(var + 1e-5f);
  float4 gg = *(const float4*)(g + lane * 4);
  float4 bb = *(const float4*)(b + lane * 4);
  float y0 = (v.x - mu) * rs * gg.x + bb.x;
  float y1 = (v.y - mu) * rs * gg.y + bb.y;
  float y2 = (v.z - mu) * rs * gg.z + bb.z;
  float y3 = (v.w - mu) * rs * gg.w + bb.w;
  uint2 o;
  o.x = (unsigned)f2bf(y0) | ((unsigned)f2bf(y1) << 16);
  o.y = (unsigned)f2bf(y2) | ((unsigned)f2bf(y3) << 16);
  *(uint2*)(x + (size_t)row * 128 + lane * 2) = o;
}

// ---------- K2: slots = mu + exp(logsigma)*noise ----------
__global__ __launch_bounds__(256) void k_init(const float* __restrict__ mu,
                                              const float* __restrict__ ls,
                                              const float* __restrict__ noise,
                                              float* __restrict__ slots) {
  int i = blockIdx.x * 256 + threadIdx.x;
  int sd = i & 2047;
  slots[i] = mu[sd] + expf(ls[sd]) * noise[i];
}

// ---------- K3: qw = LN(slots)@WqT@Wk * scale ; grid (64, 2), 4 slots/block ----------
__global__ __launch_bounds__(512) void k_qw2(const float* __restrict__ slots,
                                             const float* __restrict__ g,
                                             const float* __restrict__ b,
                                             const float* __restrict__ WqT,
                                             const float* __restrict__ Wk,
                                             float* __restrict__ qw) {
  __shared__ float ln[4][256];
  __shared__ float q[4][256];
  __shared__ float red[16];
  int n = blockIdx.x, sg = blockIdx.y * 4;
  int tid = threadIdx.x;
  {  // LN: 128 threads per slot
    int sl = tid >> 7, qq = tid & 127;
    const float* sp = slots + ((size_t)n * 8 + sg + sl) * 256;
    float v0 = sp[qq], v1 = sp[qq + 128];
    float ps = wsum(v0 + v1);
    float pq = wsum(v0 * v0 + v1 * v1);
    int wid = tid >> 6;
    if ((tid & 63) == 0) { red[wid] = ps; red[8 + wid] = pq; }
    __syncthreads();
    float ssum = red[sl * 2] + red[sl * 2 + 1];
    float sqq  = red[8 + sl * 2] + red[8 + sl * 2 + 1];
    float mu = ssum * (1.f / 256.f);
    float var = sqq * (1.f / 256.f) - mu * mu;
    float rs = rsqrtf(var + 1e-5f);
    ln[sl][qq]       = (v0 - mu) * rs * g[qq] + b[qq];
    ln[sl][qq + 128] = (v1 - mu) * rs * g[qq + 128] + b[qq + 128];
  }
  __syncthreads();
  int e = tid & 255, h = tid >> 8;
  {  // q = ln @ WqT
    float a0 = 0.f, a1 = 0.f;
    for (int d = 0; d < 256; ++d) {
      float w = WqT[d * 256 + e];
      a0 += ln[h * 2][d] * w;
      a1 += ln[h * 2 + 1][d] * w;
    }
    q[h * 2][e] = a0;
    q[h * 2 + 1][e] = a1;
  }
  __syncthreads();
  {  // qw = q @ Wk * scale   (Wk[e][d] read coalesced over d-threads)
    float a0 = 0.f, a1 = 0.f;
    for (int ee = 0; ee < 256; ++ee) {
      float w = Wk[(size_t)ee * 256 + e];
      a0 += q[h * 2][ee] * w;
      a1 += q[h * 2 + 1][ee] * w;
    }
    qw[((size_t)n * 8 + sg + h * 2) * 256 + e]     = a0 * 0.0625f;
    qw[((size_t)n * 8 + sg + h * 2 + 1) * 256 + e] = a1 * 0.0625f;
  }
}

// ---------- K4: logits[n,s,t] = sum_d qw[n,s,d] * x[n,t,d] ----------
__global__ __launch_bounds__(256) void k_logits(const unsigned* __restrict__ x,
                                                const float* __restrict__ qwp,
                                                float* __restrict__ logits) {
  __shared__ float qws[8][256];
  __shared__ unsigned xs[64][129];
  int n = blockIdx.y, t0 = blockIdx.x * 64;
  int tid = threadIdx.x;
  for (int i = tid; i < 2048; i += 256) qws[i >> 8][i & 255] = qwp[(size_t)n * 2048 + i];
  const unsigned* xp = x + ((size_t)n * TOKENS + t0) * 128;
#pragma unroll
  for (int it = 0; it < 16; ++it) {
    int tok = it * 4 + (tid >> 6);
    int w0 = (tid & 63) * 2;
    uint2 v = *(const uint2*)(xp + (size_t)tok * 128 + w0);
    xs[tok][w0] = v.x;
    xs[tok][w0 + 1] = v.y;
  }
  __syncthreads();
  int tl = tid & 63, wv = tid >> 6;
  float a0 = 0.f, a1 = 0.f;
#pragma unroll 4
  for (int c = 0; c < 64; ++c) {
    unsigned p0 = xs[tl][2 * c], p1 = xs[tl][2 * c + 1];
    float4 w0 = *(const float4*)&qws[wv][4 * c];
    float4 w1 = *(const float4*)&qws[wv + 4][4 * c];
    float x0 = bflo(p0), x1 = bfhi(p0), x2 = bflo(p1), x3 = bfhi(p1);
    a0 += x0 * w0.x + x1 * w0.y + x2 * w0.z + x3 * w0.w;
    a1 += x0 * w1.x + x1 * w1.y + x2 * w1.z + x3 * w1.w;
  }
  size_t ob = ((size_t)n * 8 + wv) * TOKENS + t0 + tl;
  logits[ob] = a0;
  logits[ob + (size_t)4 * TOKENS] = a1;
}

// ---------- K5: softmax over t (in place) ----------
__global__ __launch_bounds__(256) void k_softmax(float* __restrict__ L) {
  __shared__ float red[8];
  size_t base = (size_t)blockIdx.x * TOKENS;
  int tid = threadIdx.x, wid = tid >> 6, lane = tid & 63;
  float4 v[4];
  float m = -3.4e38f;
#pragma unroll
  for (int k = 0; k < 4; ++k) {
    v[k] = *(const float4*)(L + base + (size_t)(k * 256 + tid) * 4);
    m = fmaxf(m, fmaxf(fmaxf(v[k].x, v[k].y), fmaxf(v[k].z, v[k].w)));
  }
  m = wmax(m);
  if (lane == 0) red[wid] = m;
  __syncthreads();
  m = fmaxf(fmaxf(red[0], red[1]), fmaxf(red[2], red[3]));
  float ssum = 0.f;
#pragma unroll
  for (int k = 0; k < 4; ++k) {
    v[k].x = expf(v[k].x - m); v[k].y = expf(v[k].y - m);
    v[k].z = expf(v[k].z - m); v[k].w = expf(v[k].w - m);
    ssum += v[k].x + v[k].y + v[k].z + v[k].w;
  }
  ssum = wsum(ssum);
  if (lane == 0) red[4 + wid] = ssum;
  __syncthreads();
  ssum = red[4] + red[5] + red[6] + red[7];
  float inv = 1.f / (ssum * (1.f + 1e-8f));
#pragma unroll
  for (int k = 0; k < 4; ++k) {
    v[k].x *= inv; v[k].y *= inv; v[k].z *= inv; v[k].w *= inv;
    *(float4*)(L + base + (size_t)(k * 256 + tid) * 4) = v[k];
  }
}

// ---------- K6: partial AX over token chunks ----------
__global__ __launch_bounds__(128) void k_ax(const unsigned* __restrict__ x,
                                            const float* __restrict__ attn,
                                            float* __restrict__ part) {
  __shared__ float at[8][128];
  int n = blockIdx.y, c = blockIdx.x, t0 = c * 128;
  int tid = threadIdx.x;
  for (int i = tid; i < 1024; i += 128)
    at[i >> 7][i & 127] = attn[((size_t)n * 8 + (i >> 7)) * TOKENS + t0 + (i & 127)];
  __syncthreads();
  const unsigned* xp = x + ((size_t)n * TOKENS + t0) * 128 + tid;
  float a0[8] = {0, 0, 0, 0, 0, 0, 0, 0};
  float a1[8] = {0, 0, 0, 0, 0, 0, 0, 0};
  for (int t = 0; t < 128; ++t) {
    unsigned p = xp[(size_t)t * 128];
    float xl = bflo(p), xh = bfhi(p);
#pragma unroll
    for (int s = 0; s < 8; ++s) {
      float w = at[s][t];
      a0[s] += w * xl;
      a1[s] += w * xh;
    }
  }
  float* pp = part + (((size_t)n * NCHUNK + c) * 8) * 256;
#pragma unroll
  for (int s = 0; s < 8; ++s) {
    pp[s * 256 + tid * 2]     = a0[s];
    pp[s * 256 + tid * 2 + 1] = a1[s];
  }
}

// ---------- K7: update (4 slots/block): reduce, Wv, GRU, LN, MLP ----------
// grid (64, 2), 512 threads. All weights pre-transposed: WT[d][j].
__global__ __launch_bounds__(512) void k_update2(
    const float* __restrict__ part, const float* __restrict__ slots_in,
    const float* __restrict__ WvT, const float* __restrict__ WihT,
    const float* __restrict__ WhhT, const float* __restrict__ b_ih,
    const float* __restrict__ b_hh, const float* __restrict__ W1T,
    const float* __restrict__ b1, const float* __restrict__ W2T,
    const float* __restrict__ b2, const float* __restrict__ g2,
    const float* __restrict__ bt2, float* __restrict__ slots_out) {
  __shared__ float ax[4][256];
  __shared__ float sp[4][256];
  __shared__ float upd[4][256];
  __shared__ float gi[4][768];
  __shared__ float gh[4][768];
  __shared__ float sn[4][256];
  __shared__ float lnv[4][256];
  __shared__ float hid[4][256];
  __shared__ float red[16];
  int n = blockIdx.x, sg = blockIdx.y * 4;
  int tid = threadIdx.x;
  // 1. reduce partial chunks + load slots_prev (coalesced over d)
  for (int i = tid; i < 1024; i += 512) {
    int sl = i >> 8, d = i & 255;
    const float* pp = part + (((size_t)n * NCHUNK) * 8 + sg + sl) * 256 + d;
    float a = 0.f;
#pragma unroll
    for (int c = 0; c < NCHUNK; ++c) a += pp[(size_t)c * 2048];
    ax[sl][d] = a;
    sp[sl][d] = slots_in[((size_t)n * 8 + sg + sl) * 256 + d];
  }
  __syncthreads();
  int e = tid & 255, h = tid >> 8;
  // 2. upd = ax @ WvT (WvT[d][e] coalesced)
  {
    float a0 = 0.f, a1 = 0.f;
    for (int d = 0; d < 256; ++d) {
      float w = WvT[d * 256 + e];
      a0 += ax[h * 2][d] * w;
      a1 += ax[h * 2 + 1][d] * w;
    }
    upd[h * 2][e] = a0;
    upd[h * 2 + 1][e] = a1;
  }
  __syncthreads();
  // 3. gi/gh: 1536 rows, 3 per thread, warp-uniform ih-branch
  for (int jj = tid; jj < 1536; jj += 512) {
    bool ihs = jj < 768;
    int j = ihs ? jj : jj - 768;
    const float* WT = ihs ? WihT : WhhT;
    const float* src = ihs ? &upd[0][0] : &sp[0][0];
    float a0 = 0.f, a1 = 0.f, a2 = 0.f, a3 = 0.f;
    for (int d = 0; d < 256; ++d) {
      float w = WT[(size_t)d * 768 + j];
      a0 += src[d] * w;
      a1 += src[256 + d] * w;
      a2 += src[512 + d] * w;
      a3 += src[768 + d] * w;
    }
    float bb = ihs ? b_ih[j] : b_hh[j];
    float* dst = ihs ? &gi[0][0] : &gh[0][0];
    dst[j] = a0 + bb;
    dst[768 + j] = a1 + bb;
    dst[1536 + j] = a2 + bb;
    dst[2304 + j] = a3 + bb;
  }
  __syncthreads();
  // 4. gates -> sn
  for (int i = tid; i < 1024; i += 512) {
    int sl = i >> 8, j = i & 255;
    float r = sigmf(gi[sl][j] + gh[sl][j]);
    float z = sigmf(gi[sl][j + 256] + gh[sl][j + 256]);
    float hh = tanhf(gi[sl][j + 512] + r * gh[sl][j + 512]);
    sn[sl][j] = (1.f - z) * hh + z * sp[sl][j];
  }
  __syncthreads();
  // 5. LN(sn): 128 threads per slot
  {
    int sl = tid >> 7, qq = tid & 127;
    float v0 = sn[sl][qq], v1 = sn[sl][qq + 128];
    float ps = wsum(v0 + v1);
    float pq = wsum(v0 * v0 + v1 * v1);
    int wid = tid >> 6;
    if ((tid & 63) == 0) { red[wid] = ps; red[8 + wid] = pq; }
    __syncthreads();
    float ssum = red[sl * 2] + red[sl * 2 + 1];
    float sqq  = red[8 + sl * 2] + red[8 + sl * 2 + 1];
    float mu = ssum * (1.f / 256.f);
    float var = sqq * (1.f / 256.f) - mu * mu;
    float rs = rsqrtf(var + 1e-5f);
    lnv[sl][qq]       = (v0 - mu) * rs * g2[qq] + bt2[qq];
    lnv[sl][qq + 128] = (v1 - mu) * rs * g2[qq + 128] + bt2[qq + 128];
  }
  __syncthreads();
  // 6. hid = relu(lnv @ W1T + b1)
  {
    float a0 = 0.f, a1 = 0.f;
    for (int d = 0; d < 256; ++d) {
      float w = W1T[d * 256 + e];
      a0 += lnv[h * 2][d] * w;
      a1 += lnv[h * 2 + 1][d] * w;
    }
    hid[h * 2][e]     = fmaxf(a0 + b1[e], 0.f);
    hid[h * 2 + 1][e] = fmaxf(a1 + b1[e], 0.f);
  }
  __syncthreads();
  // 7. out = sn + hid @ W2T + b2
  {
    float a0 = 0.f, a1 = 0.f;
    for (int d = 0; d < 256; ++d) {
      float w = W2T[d * 256 + e];
      a0 += hid[h * 2][d] * w;
      a1 += hid[h * 2 + 1][d] * w;
    }
    slots_out[((size_t)n * 8 + sg + h * 2) * 256 + e]     = sn[h * 2][e] + a0 + b2[e];
    slots_out[((size_t)n * 8 + sg + h * 2 + 1) * 256 + e] = sn[h * 2 + 1][e] + a1 + b2[e];
  }
}

extern "C" void kernel_launch(void* const* d_in, const int* in_sizes, int n_in,
                              void* d_out, int out_size, void* d_ws, size_t ws_size,
                              hipStream_t stream) {
  (void)in_sizes; (void)n_in; (void)out_size; (void)ws_size;
  const float* inputs = (const float*)d_in[0];
  const float* noise  = (const float*)d_in[1];
  const float* smu    = (const float*)d_in[2];
  const float* slsig  = (const float*)d_in[3];
  const float* Wq     = (const float*)d_in[4];
  const float* Wk     = (const float*)d_in[5];
  const float* Wv     = (const float*)d_in[6];
  const float* W_ih   = (const float*)d_in[7];
  const float* W_hh   = (const float*)d_in[8];
  const float* b_ih   = (const float*)d_in[9];
  const float* b_hh   = (const float*)d_in[10];
  const float* W1     = (const float*)d_in[11];
  const float* b1     = (const float*)d_in[12];
  const float* W2     = (const float*)d_in[13];
  const float* b2     = (const float*)d_in[14];
  const float* lin_g  = (const float*)d_in[15];
  const float* lin_b  = (const float*)d_in[16];
  const float* lsl_g  = (const float*)d_in[17];
  const float* lsl_b  = (const float*)d_in[18];
  const float* lml_g  = (const float*)d_in[19];
  const float* lml_b  = (const float*)d_in[20];
  float* out = (float*)d_out;
  char* ws = (char*)d_ws;
  unsigned* x   = (unsigned*)ws;                       // 134217728 B
  float* logits = (float*)(ws + 134217728);            // 8388608 B
  float* qw     = (float*)(ws + 142606336);            // 524288 B
  float* part   = (float*)(ws + 143130624);            // 16777216 B
  float* WqT    = (float*)(ws + 159907840);            // 262144 B
  float* WvT    = (float*)(ws + 160169984);            // 262144 B
  float* WihT   = (float*)(ws + 160432128);            // 786432 B
  float* WhhT   = (float*)(ws + 161218560);            // 786432 B
  float* W1T    = (float*)(ws + 162004992);            // 262144 B
  float* W2T    = (float*)(ws + 162267136);            // 262144 B

  // one-time weight transposes (graph-captured, cheap)
  k_tr<<<dim3(8, 8), 256, 0, stream>>>(Wq, WqT, 256, 256);
  k_tr<<<dim3(8, 8), 256, 0, stream>>>(Wv, WvT, 256, 256);
  k_tr<<<dim3(8, 24), 256, 0, stream>>>(W_ih, WihT, 768, 256);
  k_tr<<<dim3(8, 24), 256, 0, stream>>>(W_hh, WhhT, 768, 256);
  k_tr<<<dim3(8, 8), 256, 0, stream>>>(W1, W1T, 256, 256);
  k_tr<<<dim3(8, 8), 256, 0, stream>>>(W2, W2T, 256, 256);

  k_ln_in<<<dim3(BATCH * TOKENS / 4), 256, 0, stream>>>(inputs, lin_g, lin_b, x);
  k_init<<<dim3(512), 256, 0, stream>>>(smu, slsig, noise, out);
  for (int it = 0; it < 3; ++it) {
    k_qw2<<<dim3(BATCH, 2), 512, 0, stream>>>(out, lsl_g, lsl_b, WqT, Wk, qw);
    k_logits<<<dim3(64, BATCH), 256, 0, stream>>>(x, qw, logits);
    k_softmax<<<dim3(512), 256, 0, stream>>>(logits);
    k_ax<<<dim3(NCHUNK, BATCH), 128, 0, stream>>>(x, logits, part);
    k_update2<<<dim3(BATCH, 2), 512, 0, stream>>>(part, out, WvT, WihT, WhhT, b_ih,
                                                  b_hh, W1T, b1, W2T, b2, lml_g, lml_b, out);
  }
}